// Round 1
// baseline (110.082 us; speedup 1.0000x reference)
//
#include <hip/hip_runtime.h>
#include <math.h>

#define DD 1024   // total dim
#define NN 128    // nodes
#define BB 8      // batch
#define KNBR 8    // neighbors
#define NH 8      // heads
#define LL 128    // latent

// ---------------------------------------------------------------------------
// Kernel 1: Y[mat] = relu(E @ W[mat] + b[mat]) for mat in {l, a, h}
// E: [1024,1024] row-major (B*N, D). W: [D,D] row-major. Y: 3 x [1024,1024].
// 64x64 tile per block, 256 threads, 4x4 per thread, K-step 32.
// ---------------------------------------------------------------------------
__global__ __launch_bounds__(256)
void gemm3_relu(const float* __restrict__ E,
                const float* __restrict__ Wl, const float* __restrict__ bl,
                const float* __restrict__ Wa, const float* __restrict__ ba,
                const float* __restrict__ Wh, const float* __restrict__ bh,
                float* __restrict__ Y) {
  const int mat = blockIdx.z;
  const float* W    = (mat == 0) ? Wl : (mat == 1) ? Wa : Wh;
  const float* bias = (mat == 0) ? bl : (mat == 1) ? ba : bh;
  float* Yout = Y + (size_t)mat * DD * DD;

  // A stored transposed: As[k][m]; pad to 68 so row stride = 272B (16B-aligned)
  __shared__ float As[32][68];
  __shared__ float Bs[32][68];

  const int tid = threadIdx.x;
  const int tx = tid & 15, ty = tid >> 4;
  const int row0 = blockIdx.y * 64;
  const int col0 = blockIdx.x * 64;

  // staging coords
  const int am  = tid >> 2;        // 0..63 (row within A tile)
  const int akb = (tid & 3) * 8;   // k-offset 0,8,16,24
  const int bk  = tid >> 3;        // 0..31 (k row of B tile)
  const int bnb = (tid & 7) * 8;   // col offset 0..56

  float acc[4][4] = {};

  for (int k0 = 0; k0 < DD; k0 += 32) {
    // global loads first (hide latency across the barrier)
    const float* arow_p = &E[(size_t)(row0 + am) * DD + k0 + akb];
    float4 a0 = *(const float4*)(arow_p);
    float4 a1 = *(const float4*)(arow_p + 4);
    const float* brow_p = &W[(size_t)(k0 + bk) * DD + col0 + bnb];
    float4 b0 = *(const float4*)(brow_p);
    float4 b1 = *(const float4*)(brow_p + 4);

    __syncthreads();  // previous tile's compute done before overwrite
    As[akb + 0][am] = a0.x; As[akb + 1][am] = a0.y;
    As[akb + 2][am] = a0.z; As[akb + 3][am] = a0.w;
    As[akb + 4][am] = a1.x; As[akb + 5][am] = a1.y;
    As[akb + 6][am] = a1.z; As[akb + 7][am] = a1.w;
    *(float4*)&Bs[bk][bnb]     = b0;
    *(float4*)&Bs[bk][bnb + 4] = b1;
    __syncthreads();

    #pragma unroll 8
    for (int kk = 0; kk < 32; ++kk) {
      float4 av = *(const float4*)&As[kk][ty * 4];
      float4 bv = *(const float4*)&Bs[kk][tx * 4];
      float a[4] = {av.x, av.y, av.z, av.w};
      float b[4] = {bv.x, bv.y, bv.z, bv.w};
      #pragma unroll
      for (int i = 0; i < 4; ++i)
        #pragma unroll
        for (int j = 0; j < 4; ++j)
          acc[i][j] = fmaf(a[i], b[j], acc[i][j]);
    }
  }

  // epilogue: + bias, relu, store
  #pragma unroll
  for (int i = 0; i < 4; ++i) {
    const int row = row0 + ty * 4 + i;
    const int col = col0 + tx * 4;
    float4 v;
    v.x = fmaxf(acc[i][0] + bias[col + 0], 0.f);
    v.y = fmaxf(acc[i][1] + bias[col + 1], 0.f);
    v.z = fmaxf(acc[i][2] + bias[col + 2], 0.f);
    v.w = fmaxf(acc[i][3] + bias[col + 3], 0.f);
    *(float4*)&Yout[(size_t)row * DD + col] = v;
  }
}

// ---------------------------------------------------------------------------
// Kernel 2: per (b,i) node -- gather neighbor rows of Ya/Yh, per-head softmax,
// head-mean output. One block of 256 threads per node; 8 groups of 32 lanes,
// one group per head (L=128, 4 elements per lane).
// ---------------------------------------------------------------------------
__global__ __launch_bounds__(256)
void colight_epilogue(const float* __restrict__ adj,
                      const float* __restrict__ Y,
                      float* __restrict__ out) {
  const int bi = blockIdx.x;       // 0..1023
  const int b  = bi >> 7;

  __shared__ int   idxs[KNBR];
  __shared__ float sA[DD];
  __shared__ float sH[DD];
  __shared__ float sL[DD];
  __shared__ float sPart[NH][LL];

  const int t = threadIdx.x;

  // find the one-hot neighbor indices: group k = t>>5 scans its 128-row
  const float* arow = adj + (size_t)bi * KNBR * NN;
  {
    const int k = t >> 5, j = t & 31;
    #pragma unroll
    for (int n = j; n < NN; n += 32)
      if (arow[k * NN + n] > 0.5f) idxs[k] = n;
  }
  __syncthreads();

  const float* Yl = Y;
  const float* Ya = Y + (size_t)DD * DD;
  const float* Yh = Y + 2 * (size_t)DD * DD;
  const int rbase = b * NN;

  int ridx[KNBR];
  #pragma unroll
  for (int k = 0; k < KNBR; ++k) ridx[k] = rbase + idxs[k];

  // gather + sum 8 neighbor rows of Ya and Yh; load own Yl row
  #pragma unroll
  for (int d = t; d < DD; d += 256) {
    float sa = 0.f, sh = 0.f;
    #pragma unroll
    for (int k = 0; k < KNBR; ++k) {
      const size_t rr = (size_t)ridx[k] * DD + d;
      sa += Ya[rr];
      sh += Yh[rr];
    }
    sA[d] = sa;
    sH[d] = sh;
    sL[d] = Yl[(size_t)bi * DD + d];
  }
  __syncthreads();

  // per-head softmax over L=128: head h = t>>5, lane j = t&31, 4 elems/lane
  const int h = t >> 5, j = t & 31;
  float z[4];
  float mx = -1e30f;
  #pragma unroll
  for (int q = 0; q < 4; ++q) {
    const int l = j + q * 32;
    z[q] = sL[l * NH + h] * sA[l * NH + h];
    mx = fmaxf(mx, z[q]);
  }
  #pragma unroll
  for (int m = 1; m <= 16; m <<= 1)
    mx = fmaxf(mx, __shfl_xor(mx, m, 32));

  float se = 0.f;
  #pragma unroll
  for (int q = 0; q < 4; ++q) {
    z[q] = expf(z[q] - mx);
    se += z[q];
  }
  #pragma unroll
  for (int m = 1; m <= 16; m <<= 1)
    se += __shfl_xor(se, m, 32);
  const float inv = 1.f / se;

  #pragma unroll
  for (int q = 0; q < 4; ++q) {
    const int l = j + q * 32;
    sPart[h][l] = z[q] * inv * sH[l * NH + h] * 0.125f;  // mean over 8 heads
  }
  __syncthreads();

  // reduce the 8 head-partials and store out[b,i,l]
  if (t < LL) {
    float o = 0.f;
    #pragma unroll
    for (int hh = 0; hh < NH; ++hh) o += sPart[hh][t];
    out[(size_t)bi * LL + t] = o;
  }
}

// ---------------------------------------------------------------------------
extern "C" void kernel_launch(void* const* d_in, const int* in_sizes, int n_in,
                              void* d_out, int out_size, void* d_ws, size_t ws_size,
                              hipStream_t stream) {
  const float* E   = (const float*)d_in[0];
  const float* adj = (const float*)d_in[1];
  const float* Wl  = (const float*)d_in[2];
  const float* bl  = (const float*)d_in[3];
  const float* Wa  = (const float*)d_in[4];
  const float* ba  = (const float*)d_in[5];
  const float* Wh  = (const float*)d_in[6];
  const float* bh  = (const float*)d_in[7];
  float* out = (float*)d_out;
  float* Y   = (float*)d_ws;   // needs 3 * 1024 * 1024 * 4B = 12 MB scratch

  dim3 g1(DD / 64, DD / 64, 3);   // 16 x 16 x 3 = 768 blocks
  gemm3_relu<<<g1, dim3(256), 0, stream>>>(E, Wl, bl, Wa, ba, Wh, bh, Y);

  colight_epilogue<<<dim3(BB * NN), dim3(256), 0, stream>>>(adj, Y, out);
}

// Round 2
// 47.592 us; speedup vs baseline: 2.3130x; 2.3130x over previous
//
#include <hip/hip_runtime.h>
#include <math.h>

#define DD 1024   // total dim
#define NN 128    // nodes
#define BB 8      // batch
#define KNBR 8    // neighbors
#define NH 8      // heads
#define LL 128    // latent

typedef __attribute__((ext_vector_type(8))) short short8v;
typedef __attribute__((ext_vector_type(4))) float f32x4;

__device__ __forceinline__ unsigned short f2bf(float x) {
  unsigned u = __float_as_uint(x);
  unsigned r = u + 0x7fff + ((u >> 16) & 1);   // round-to-nearest-even
  return (unsigned short)(r >> 16);
}

// ---------------------------------------------------------------------------
// Convert E (1024x1024 fp32) -> bf16, linear. 8 elems/thread.
// ---------------------------------------------------------------------------
__global__ __launch_bounds__(256)
void convert_e(const float* __restrict__ E, unsigned short* __restrict__ Eb) {
  const int i = (blockIdx.x * 256 + threadIdx.x) * 8;
  float4 a = *(const float4*)&E[i];
  float4 b = *(const float4*)&E[i + 4];
  union { unsigned short u[8]; uint4 v; } o;
  o.u[0] = f2bf(a.x); o.u[1] = f2bf(a.y); o.u[2] = f2bf(a.z); o.u[3] = f2bf(a.w);
  o.u[4] = f2bf(b.x); o.u[5] = f2bf(b.y); o.u[6] = f2bf(b.z); o.u[7] = f2bf(b.w);
  *(uint4*)&Eb[i] = o.v;
}

// ---------------------------------------------------------------------------
// Convert + transpose W[mat] (KxN fp32, row-major) -> Wt[mat] (NxK bf16).
// 64x64 tiles via LDS. grid (16,16,3), 256 threads.
// ---------------------------------------------------------------------------
__global__ __launch_bounds__(256)
void convert_transpose_w(const float* __restrict__ Wl,
                         const float* __restrict__ Wa,
                         const float* __restrict__ Wh,
                         unsigned short* __restrict__ Wt) {
  const int mat = blockIdx.z;
  const float* W = (mat == 0) ? Wl : (mat == 1) ? Wa : Wh;
  unsigned short* out = Wt + (size_t)mat * DD * DD;

  __shared__ unsigned short tile[64][65];
  const int tx = threadIdx.x & 15, ty = threadIdx.x >> 4;
  const int r0 = blockIdx.y * 64, c0 = blockIdx.x * 64;

  #pragma unroll
  for (int i = 0; i < 4; ++i) {
    const int r = ty + i * 16;
    float4 v = *(const float4*)&W[(size_t)(r0 + r) * DD + c0 + tx * 4];
    tile[r][tx * 4 + 0] = f2bf(v.x);
    tile[r][tx * 4 + 1] = f2bf(v.y);
    tile[r][tx * 4 + 2] = f2bf(v.z);
    tile[r][tx * 4 + 3] = f2bf(v.w);
  }
  __syncthreads();
  #pragma unroll
  for (int i = 0; i < 4; ++i) {
    const int rr = ty + i * 16;   // output row = W column c0+rr
    ushort4 o;
    o.x = tile[tx * 4 + 0][rr];
    o.y = tile[tx * 4 + 1][rr];
    o.z = tile[tx * 4 + 2][rr];
    o.w = tile[tx * 4 + 3][rr];
    *(ushort4*)&out[(size_t)(c0 + rr) * DD + r0 + tx * 4] = o;
  }
}

// ---------------------------------------------------------------------------
// MFMA GEMM: Y[mat] = relu(Eb @ W[mat] + b[mat]), bf16 in / fp32 out.
// 128x128 tile, BK=32, 512 threads = 8 waves (2/SIMD), wave tile 64x32.
// A: Eb [M,K] row-major bf16. B: Wt [N,K] row-major bf16 (W transposed).
// grid (8,8,3).
// ---------------------------------------------------------------------------
__global__ __launch_bounds__(512)
void gemm3_mfma(const unsigned short* __restrict__ Eb,
                const unsigned short* __restrict__ Wt,
                const float* __restrict__ bl, const float* __restrict__ ba,
                const float* __restrict__ bh, float* __restrict__ Y) {
  const int mat = blockIdx.z;
  const unsigned short* Bg = Wt + (size_t)mat * DD * DD;
  const float* bias = (mat == 0) ? bl : (mat == 1) ? ba : bh;
  float* Yout = Y + (size_t)mat * DD * DD;

  __shared__ unsigned short As[128 * 32];
  __shared__ unsigned short Bs[128 * 32];

  const int t = threadIdx.x;
  const int lane = t & 63;
  const int w = t >> 6;            // wave 0..7
  const int wr = w >> 2;           // 0..1  -> 64-row half
  const int wc = w & 3;            // 0..3  -> 32-col quarter
  const int brow = blockIdx.y * 128, bcol = blockIdx.x * 128;

  // staging: thread t -> tile row t>>2, k-offset (t&3)*8. 512x16B = one 8KB tile.
  const int srow = t >> 2, skoff = (t & 3) * 8;
  const unsigned short* gA = Eb + (size_t)(brow + srow) * DD + skoff;
  const unsigned short* gB = Bg + (size_t)(bcol + srow) * DD + skoff;
  // wave-uniform LDS base (lane*16B appended by HW): wave w covers rows w*16..w*16+15
  unsigned short* lA = As + w * 16 * 32;
  unsigned short* lB = Bs + w * 16 * 32;

  const int lrow = lane & 15, lg = lane >> 4;

  f32x4 acc[4][2] = {};

  for (int k0 = 0; k0 < DD; k0 += 32) {
    __builtin_amdgcn_global_load_lds(
        (const __attribute__((address_space(1))) void*)(gA + k0),
        (__attribute__((address_space(3))) void*)lA, 16, 0, 0);
    __builtin_amdgcn_global_load_lds(
        (const __attribute__((address_space(1))) void*)(gB + k0),
        (__attribute__((address_space(3))) void*)lB, 16, 0, 0);
    __syncthreads();   // compiler drains vmcnt before barrier -> tiles ready

    short8v a[4], b[2];
    #pragma unroll
    for (int m = 0; m < 4; ++m)
      a[m] = *(const short8v*)&As[(wr * 64 + m * 16 + lrow) * 32 + lg * 8];
    #pragma unroll
    for (int n = 0; n < 2; ++n)
      b[n] = *(const short8v*)&Bs[(wc * 32 + n * 16 + lrow) * 32 + lg * 8];

    #pragma unroll
    for (int m = 0; m < 4; ++m)
      #pragma unroll
      for (int n = 0; n < 2; ++n)
        acc[m][n] = __builtin_amdgcn_mfma_f32_16x16x32_bf16(a[m], b[n], acc[m][n], 0, 0, 0);

    __syncthreads();   // compute done before next stage overwrites
  }

  // epilogue: bias + relu, fp32 store (C/D: col = lane&15, row = (lane>>4)*4 + j)
  #pragma unroll
  for (int m = 0; m < 4; ++m) {
    #pragma unroll
    for (int n = 0; n < 2; ++n) {
      const int col = bcol + wc * 32 + n * 16 + lrow;
      const int r0  = brow + wr * 64 + m * 16 + lg * 4;
      const float bv = bias[col];
      #pragma unroll
      for (int j = 0; j < 4; ++j)
        Yout[(size_t)(r0 + j) * DD + col] = fmaxf(acc[m][n][j] + bv, 0.f);
    }
  }
}

// ---------------------------------------------------------------------------
// Kernel 2: per (b,i) node -- gather neighbor rows of Ya/Yh, per-head softmax,
// head-mean output. (unchanged from passing R0 version)
// ---------------------------------------------------------------------------
__global__ __launch_bounds__(256)
void colight_epilogue(const float* __restrict__ adj,
                      const float* __restrict__ Y,
                      float* __restrict__ out) {
  const int bi = blockIdx.x;       // 0..1023
  const int b  = bi >> 7;

  __shared__ int   idxs[KNBR];
  __shared__ float sA[DD];
  __shared__ float sH[DD];
  __shared__ float sL[DD];
  __shared__ float sPart[NH][LL];

  const int t = threadIdx.x;

  const float* arow = adj + (size_t)bi * KNBR * NN;
  {
    const int k = t >> 5, j = t & 31;
    #pragma unroll
    for (int n = j; n < NN; n += 32)
      if (arow[k * NN + n] > 0.5f) idxs[k] = n;
  }
  __syncthreads();

  const float* Yl = Y;
  const float* Ya = Y + (size_t)DD * DD;
  const float* Yh = Y + 2 * (size_t)DD * DD;
  const int rbase = b * NN;

  int ridx[KNBR];
  #pragma unroll
  for (int k = 0; k < KNBR; ++k) ridx[k] = rbase + idxs[k];

  #pragma unroll
  for (int d = t; d < DD; d += 256) {
    float sa = 0.f, sh = 0.f;
    #pragma unroll
    for (int k = 0; k < KNBR; ++k) {
      const size_t rr = (size_t)ridx[k] * DD + d;
      sa += Ya[rr];
      sh += Yh[rr];
    }
    sA[d] = sa;
    sH[d] = sh;
    sL[d] = Yl[(size_t)bi * DD + d];
  }
  __syncthreads();

  const int h = t >> 5, j = t & 31;
  float z[4];
  float mx = -1e30f;
  #pragma unroll
  for (int q = 0; q < 4; ++q) {
    const int l = j + q * 32;
    z[q] = sL[l * NH + h] * sA[l * NH + h];
    mx = fmaxf(mx, z[q]);
  }
  #pragma unroll
  for (int m = 1; m <= 16; m <<= 1)
    mx = fmaxf(mx, __shfl_xor(mx, m, 32));

  float se = 0.f;
  #pragma unroll
  for (int q = 0; q < 4; ++q) {
    z[q] = expf(z[q] - mx);
    se += z[q];
  }
  #pragma unroll
  for (int m = 1; m <= 16; m <<= 1)
    se += __shfl_xor(se, m, 32);
  const float inv = 1.f / se;

  #pragma unroll
  for (int q = 0; q < 4; ++q) {
    const int l = j + q * 32;
    sPart[h][l] = z[q] * inv * sH[l * NH + h] * 0.125f;
  }
  __syncthreads();

  if (t < LL) {
    float o = 0.f;
    #pragma unroll
    for (int hh = 0; hh < NH; ++hh) o += sPart[hh][t];
    out[(size_t)bi * LL + t] = o;
  }
}

// ---------------------------------------------------------------------------
extern "C" void kernel_launch(void* const* d_in, const int* in_sizes, int n_in,
                              void* d_out, int out_size, void* d_ws, size_t ws_size,
                              hipStream_t stream) {
  const float* E   = (const float*)d_in[0];
  const float* adj = (const float*)d_in[1];
  const float* Wl  = (const float*)d_in[2];
  const float* bl  = (const float*)d_in[3];
  const float* Wa  = (const float*)d_in[4];
  const float* ba  = (const float*)d_in[5];
  const float* Wh  = (const float*)d_in[6];
  const float* bh  = (const float*)d_in[7];
  float* out = (float*)d_out;

  char* ws = (char*)d_ws;
  float*          Y  = (float*)ws;                               // 12 MB
  unsigned short* Eb = (unsigned short*)(ws + 12 * 1024 * 1024); // 2 MB
  unsigned short* Wt = (unsigned short*)(ws + 14 * 1024 * 1024); // 6 MB

  convert_e<<<dim3(512), dim3(256), 0, stream>>>(E, Eb);
  convert_transpose_w<<<dim3(16, 16, 3), dim3(256), 0, stream>>>(Wl, Wa, Wh, Wt);
  gemm3_mfma<<<dim3(8, 8, 3), dim3(512), 0, stream>>>(Eb, Wt, bl, ba, bh, Y);
  colight_epilogue<<<dim3(BB * NN), dim3(256), 0, stream>>>(adj, Y, out);
}

// Round 3
// 36.486 us; speedup vs baseline: 3.0171x; 1.3044x over previous
//
#include <hip/hip_runtime.h>
#include <math.h>

#define DD 1024   // total dim
#define NN 128    // nodes
#define BB 8      // batch
#define KNBR 8    // neighbors
#define NH 8      // heads
#define LL 128    // latent

typedef __attribute__((ext_vector_type(8))) short short8v;
typedef __attribute__((ext_vector_type(4))) float f32x4;

#define GLDS(gptr, lptr)                                                      \
  __builtin_amdgcn_global_load_lds(                                           \
      (const __attribute__((address_space(1))) void*)(gptr),                  \
      (__attribute__((address_space(3))) void*)(lptr), 16, 0, 0)

__device__ __forceinline__ unsigned short f2bf(float x) {
  unsigned u = __float_as_uint(x);
  unsigned r = u + 0x7fff + ((u >> 16) & 1);   // round-to-nearest-even
  return (unsigned short)(r >> 16);
}

// ---------------------------------------------------------------------------
// Prep: z<3 -> convert+transpose W[z] (64x64 LDS tiles); z==3 -> convert E.
// grid (16,16,4), 256 threads.
// ---------------------------------------------------------------------------
__global__ __launch_bounds__(256)
void prep(const float* __restrict__ E,
          const float* __restrict__ Wl, const float* __restrict__ Wa,
          const float* __restrict__ Wh,
          unsigned short* __restrict__ Eb, unsigned short* __restrict__ Wt) {
  const int z = blockIdx.z;
  const int t = threadIdx.x;

  if (z == 3) {   // E convert: 256 blocks x 256 threads x 16 elems
    const int bid = blockIdx.y * 16 + blockIdx.x;
    const int i0 = bid * 4096 + t * 16;
    #pragma unroll
    for (int q = 0; q < 2; ++q) {
      const int i = i0 + q * 8;
      float4 a = *(const float4*)&E[i];
      float4 c = *(const float4*)&E[i + 4];
      union { unsigned short u[8]; uint4 v; } o;
      o.u[0] = f2bf(a.x); o.u[1] = f2bf(a.y); o.u[2] = f2bf(a.z); o.u[3] = f2bf(a.w);
      o.u[4] = f2bf(c.x); o.u[5] = f2bf(c.y); o.u[6] = f2bf(c.z); o.u[7] = f2bf(c.w);
      *(uint4*)&Eb[i] = o.v;
    }
    return;
  }

  const float* W = (z == 0) ? Wl : (z == 1) ? Wa : Wh;
  unsigned short* out = Wt + (size_t)z * DD * DD;

  __shared__ unsigned short tile[64][65];
  const int tx = t & 15, ty = t >> 4;
  const int r0 = blockIdx.y * 64, c0 = blockIdx.x * 64;

  #pragma unroll
  for (int i = 0; i < 4; ++i) {
    const int r = ty + i * 16;
    float4 v = *(const float4*)&W[(size_t)(r0 + r) * DD + c0 + tx * 4];
    tile[r][tx * 4 + 0] = f2bf(v.x);
    tile[r][tx * 4 + 1] = f2bf(v.y);
    tile[r][tx * 4 + 2] = f2bf(v.z);
    tile[r][tx * 4 + 3] = f2bf(v.w);
  }
  __syncthreads();
  #pragma unroll
  for (int i = 0; i < 4; ++i) {
    const int rr = ty + i * 16;   // output row = W column c0+rr
    ushort4 o;
    o.x = tile[tx * 4 + 0][rr];
    o.y = tile[tx * 4 + 1][rr];
    o.z = tile[tx * 4 + 2][rr];
    o.w = tile[tx * 4 + 3][rr];
    *(ushort4*)&out[(size_t)(c0 + rr) * DD + r0 + tx * 4] = o;
  }
}

// ---------------------------------------------------------------------------
// MFMA GEMM: Y[mat] = relu(Eb @ W[mat] + b[mat]), bf16 in / fp32 out.
// 64x64 tile, BK=64, 256 threads = 4 waves, wave tile 32x32.
// Double-buffered LDS with prefetch-ahead; XOR-swizzled tiles (both sides:
// pre-swizzled global source for global_load_lds + swizzled ds_read index).
// grid (16,16,3) = 768 blocks (3/CU).
// ---------------------------------------------------------------------------
__global__ __launch_bounds__(256)
void gemm3_mfma(const unsigned short* __restrict__ Eb,
                const unsigned short* __restrict__ Wt,
                const float* __restrict__ bl, const float* __restrict__ ba,
                const float* __restrict__ bh, float* __restrict__ Y) {
  const int mat = blockIdx.z;
  const unsigned short* Bg = Wt + (size_t)mat * DD * DD;
  const float* bias = (mat == 0) ? bl : (mat == 1) ? ba : bh;
  float* Yout = Y + (size_t)mat * DD * DD;

  __shared__ unsigned short As[2][64 * 64];
  __shared__ unsigned short Bs[2][64 * 64];

  const int t = threadIdx.x;
  const int lane = t & 63;
  const int w = t >> 6;            // wave 0..3
  const int wr = w >> 1, wc = w & 1;
  const int brow = blockIdx.y * 64, bcol = blockIdx.x * 64;

  // staging: thread t -> tile row (t>>3) [+32 for 2nd issue], 16B chunk (t&7).
  // swizzle: LDS row r, linear chunk q holds global chunk q ^ (r&7).
  const int srow = t >> 3;                      // 0..31
  const int sk = (((t & 7) ^ (srow & 7)) * 8);  // source k-offset (elems)
  const unsigned short* gA = Eb + (size_t)(brow + srow) * DD + sk;
  const unsigned short* gB = Bg + (size_t)(bcol + srow) * DD + sk;
  const int ldsoff = w * 512;   // elems; wave-uniform base (+ lane*16B by HW)

  const int lrow = lane & 15, lg = lane >> 4;

  // swizzled fragment indices: row r, logical chunk (kk*4+lg) -> chunk^(r&7)
  int aidx[2][2], bidx[2][2];
  #pragma unroll
  for (int kk = 0; kk < 2; ++kk)
    #pragma unroll
    for (int m = 0; m < 2; ++m) {
      const int ra = wr * 32 + m * 16 + lrow;
      aidx[kk][m] = ra * 64 + (((kk * 4 + lg) ^ (ra & 7)) * 8);
      const int rb = wc * 32 + m * 16 + lrow;
      bidx[kk][m] = rb * 64 + (((kk * 4 + lg) ^ (rb & 7)) * 8);
    }

  f32x4 acc[2][2] = {};

  // prologue: stage tile 0 into buf 0
  GLDS(gA,           &As[0][ldsoff]);
  GLDS(gA + 32 * DD, &As[0][2048 + ldsoff]);
  GLDS(gB,           &Bs[0][ldsoff]);
  GLDS(gB + 32 * DD, &Bs[0][2048 + ldsoff]);
  __syncthreads();   // drains vmcnt -> tile 0 ready

  int cur = 0;
  for (int kt = 0; kt < 16; ++kt) {
    if (kt < 15) {   // prefetch next tile into the other buffer
      const int k0 = (kt + 1) * 64;
      GLDS(gA + k0,           &As[cur ^ 1][ldsoff]);
      GLDS(gA + k0 + 32 * DD, &As[cur ^ 1][2048 + ldsoff]);
      GLDS(gB + k0,           &Bs[cur ^ 1][ldsoff]);
      GLDS(gB + k0 + 32 * DD, &Bs[cur ^ 1][2048 + ldsoff]);
    }

    short8v a[2][2], b[2][2];
    #pragma unroll
    for (int kk = 0; kk < 2; ++kk)
      #pragma unroll
      for (int m = 0; m < 2; ++m) {
        a[kk][m] = *(const short8v*)&As[cur][aidx[kk][m]];
        b[kk][m] = *(const short8v*)&Bs[cur][bidx[kk][m]];
      }

    #pragma unroll
    for (int kk = 0; kk < 2; ++kk)
      #pragma unroll
      for (int m = 0; m < 2; ++m)
        #pragma unroll
        for (int n = 0; n < 2; ++n)
          acc[m][n] = __builtin_amdgcn_mfma_f32_16x16x32_bf16(
              a[kk][m], b[kk][n], acc[m][n], 0, 0, 0);

    __syncthreads();   // drains prefetch (vmcnt 0) + all ds_reads, then barrier
    cur ^= 1;
  }

  // epilogue: bias + relu (C/D: col = lane&15, row = (lane>>4)*4 + j)
  #pragma unroll
  for (int m = 0; m < 2; ++m) {
    #pragma unroll
    for (int n = 0; n < 2; ++n) {
      const int col = bcol + wc * 32 + n * 16 + lrow;
      const int r0  = brow + wr * 32 + m * 16 + lg * 4;
      const float bv = bias[col];
      #pragma unroll
      for (int j = 0; j < 4; ++j)
        Yout[(size_t)(r0 + j) * DD + col] = fmaxf(acc[m][n][j] + bv, 0.f);
    }
  }
}

// ---------------------------------------------------------------------------
// Epilogue: per (b,i) node -- gather neighbor rows of Ya/Yh (float4,
// coalesced), per-head softmax over L=128, head-mean output.
// ---------------------------------------------------------------------------
__global__ __launch_bounds__(256)
void colight_epilogue(const float* __restrict__ adj,
                      const float* __restrict__ Y,
                      float* __restrict__ out) {
  const int bi = blockIdx.x;       // 0..1023
  const int b  = bi >> 7;

  __shared__ int   idxs[KNBR];
  __shared__ float sA[DD];
  __shared__ float sH[DD];
  __shared__ float sL[DD];
  __shared__ float sPart[NH][LL];

  const int t = threadIdx.x;

  // one-hot scan: group k = t>>5 scans its 128-float row as float4
  const float* arow = adj + (size_t)bi * KNBR * NN;
  {
    const int k = t >> 5, j = t & 31;
    float4 v = *(const float4*)&arow[k * NN + j * 4];
    const int base = j * 4;
    if (v.x > 0.5f) idxs[k] = base;
    if (v.y > 0.5f) idxs[k] = base + 1;
    if (v.z > 0.5f) idxs[k] = base + 2;
    if (v.w > 0.5f) idxs[k] = base + 3;
  }
  __syncthreads();

  const float* Yl = Y;
  const float* Ya = Y + (size_t)DD * DD;
  const float* Yh = Y + 2 * (size_t)DD * DD;
  const int rbase = b * NN;

  int ridx[KNBR];
  #pragma unroll
  for (int k = 0; k < KNBR; ++k) ridx[k] = rbase + idxs[k];

  // gather + sum 8 neighbor rows (float4 per thread, coalesced row reads)
  const int d0 = t * 4;
  {
    float ax = 0.f, ay = 0.f, az = 0.f, aw = 0.f;
    float hx = 0.f, hy = 0.f, hz = 0.f, hw = 0.f;
    #pragma unroll
    for (int k = 0; k < KNBR; ++k) {
      const size_t rr = (size_t)ridx[k] * DD + d0;
      float4 va = *(const float4*)&Ya[rr];
      float4 vh = *(const float4*)&Yh[rr];
      ax += va.x; ay += va.y; az += va.z; aw += va.w;
      hx += vh.x; hy += vh.y; hz += vh.z; hw += vh.w;
    }
    float4 sa = {ax, ay, az, aw};
    float4 sh = {hx, hy, hz, hw};
    *(float4*)&sA[d0] = sa;
    *(float4*)&sH[d0] = sh;
    *(float4*)&sL[d0] = *(const float4*)&Yl[(size_t)bi * DD + d0];
  }
  __syncthreads();

  // per-head softmax over L=128: head h = t>>5, lane j = t&31, 4 elems/lane
  const int h = t >> 5, j = t & 31;
  float z[4];
  float mx = -1e30f;
  #pragma unroll
  for (int q = 0; q < 4; ++q) {
    const int l = j + q * 32;
    z[q] = sL[l * NH + h] * sA[l * NH + h];
    mx = fmaxf(mx, z[q]);
  }
  #pragma unroll
  for (int m = 1; m <= 16; m <<= 1)
    mx = fmaxf(mx, __shfl_xor(mx, m, 32));

  float se = 0.f;
  #pragma unroll
  for (int q = 0; q < 4; ++q) {
    z[q] = expf(z[q] - mx);
    se += z[q];
  }
  #pragma unroll
  for (int m = 1; m <= 16; m <<= 1)
    se += __shfl_xor(se, m, 32);
  const float inv = 1.f / se;

  #pragma unroll
  for (int q = 0; q < 4; ++q) {
    const int l = j + q * 32;
    sPart[h][l] = z[q] * inv * sH[l * NH + h] * 0.125f;  // mean over 8 heads
  }
  __syncthreads();

  if (t < LL) {
    float o = 0.f;
    #pragma unroll
    for (int hh = 0; hh < NH; ++hh) o += sPart[hh][t];
    out[(size_t)bi * LL + t] = o;
  }
}

// ---------------------------------------------------------------------------
extern "C" void kernel_launch(void* const* d_in, const int* in_sizes, int n_in,
                              void* d_out, int out_size, void* d_ws, size_t ws_size,
                              hipStream_t stream) {
  const float* E   = (const float*)d_in[0];
  const float* adj = (const float*)d_in[1];
  const float* Wl  = (const float*)d_in[2];
  const float* bl  = (const float*)d_in[3];
  const float* Wa  = (const float*)d_in[4];
  const float* ba  = (const float*)d_in[5];
  const float* Wh  = (const float*)d_in[6];
  const float* bh  = (const float*)d_in[7];
  float* out = (float*)d_out;

  char* ws = (char*)d_ws;
  float*          Y  = (float*)ws;                               // 12 MB
  unsigned short* Eb = (unsigned short*)(ws + 12 * 1024 * 1024); // 2 MB
  unsigned short* Wt = (unsigned short*)(ws + 14 * 1024 * 1024); // 6 MB

  prep<<<dim3(16, 16, 4), dim3(256), 0, stream>>>(E, Wl, Wa, Wh, Eb, Wt);
  gemm3_mfma<<<dim3(16, 16, 3), dim3(256), 0, stream>>>(Eb, Wt, bl, ba, bh, Y);
  colight_epilogue<<<dim3(BB * NN), dim3(256), 0, stream>>>(adj, Y, out);
}

// Round 4
// 33.326 us; speedup vs baseline: 3.3032x; 1.0948x over previous
//
#include <hip/hip_runtime.h>
#include <math.h>

#define DD 1024   // total dim
#define NN 128    // nodes
#define BB 8      // batch
#define KNBR 8    // neighbors
#define NH 8      // heads
#define LL 128    // latent

typedef __attribute__((ext_vector_type(8))) short short8v;
typedef __attribute__((ext_vector_type(4))) float f32x4;

#define GLDS(gptr, lptr)                                                      \
  __builtin_amdgcn_global_load_lds(                                           \
      (const __attribute__((address_space(1))) void*)(gptr),                  \
      (__attribute__((address_space(3))) void*)(lptr), 16, 0, 0)

__device__ __forceinline__ unsigned short f2bf(float x) {
  unsigned u = __float_as_uint(x);
  unsigned r = u + 0x7fff + ((u >> 16) & 1);   // round-to-nearest-even
  return (unsigned short)(r >> 16);
}

// ---------------------------------------------------------------------------
// Prep: z<3 -> convert+transpose W[z] (64x64 LDS tiles); z==3 -> convert E.
// grid (16,16,4), 256 threads.
// ---------------------------------------------------------------------------
__global__ __launch_bounds__(256)
void prep(const float* __restrict__ E,
          const float* __restrict__ Wl, const float* __restrict__ Wa,
          const float* __restrict__ Wh,
          unsigned short* __restrict__ Eb, unsigned short* __restrict__ Wt) {
  const int z = blockIdx.z;
  const int t = threadIdx.x;

  if (z == 3) {   // E convert: 256 blocks x 256 threads x 16 elems
    const int bid = blockIdx.y * 16 + blockIdx.x;
    const int i0 = bid * 4096 + t * 16;
    #pragma unroll
    for (int q = 0; q < 2; ++q) {
      const int i = i0 + q * 8;
      float4 a = *(const float4*)&E[i];
      float4 c = *(const float4*)&E[i + 4];
      union { unsigned short u[8]; uint4 v; } o;
      o.u[0] = f2bf(a.x); o.u[1] = f2bf(a.y); o.u[2] = f2bf(a.z); o.u[3] = f2bf(a.w);
      o.u[4] = f2bf(c.x); o.u[5] = f2bf(c.y); o.u[6] = f2bf(c.z); o.u[7] = f2bf(c.w);
      *(uint4*)&Eb[i] = o.v;
    }
    return;
  }

  const float* W = (z == 0) ? Wl : (z == 1) ? Wa : Wh;
  unsigned short* out = Wt + (size_t)z * DD * DD;

  __shared__ unsigned short tile[64][65];
  const int tx = t & 15, ty = t >> 4;
  const int r0 = blockIdx.y * 64, c0 = blockIdx.x * 64;

  #pragma unroll
  for (int i = 0; i < 4; ++i) {
    const int r = ty + i * 16;
    float4 v = *(const float4*)&W[(size_t)(r0 + r) * DD + c0 + tx * 4];
    tile[r][tx * 4 + 0] = f2bf(v.x);
    tile[r][tx * 4 + 1] = f2bf(v.y);
    tile[r][tx * 4 + 2] = f2bf(v.z);
    tile[r][tx * 4 + 3] = f2bf(v.w);
  }
  __syncthreads();
  #pragma unroll
  for (int i = 0; i < 4; ++i) {
    const int rr = ty + i * 16;   // output row = W column c0+rr
    ushort4 o;
    o.x = tile[tx * 4 + 0][rr];
    o.y = tile[tx * 4 + 1][rr];
    o.z = tile[tx * 4 + 2][rr];
    o.w = tile[tx * 4 + 3][rr];
    *(ushort4*)&out[(size_t)(c0 + rr) * DD + r0 + tx * 4] = o;
  }
}

// ---------------------------------------------------------------------------
// MFMA GEMM: Y[mat] = relu(Eb @ W[mat] + b[mat]), bf16 in / fp32 out.
// 64x64 tile, BK=64, 256 threads = 4 waves, wave tile 32x32.
// Double-buffered LDS, XOR-swizzled tiles (pre-swizzled global source for
// global_load_lds + identically swizzled ds_read index).
// 1D grid 768, XCD-swizzled: XCD g gets 96 contiguous jobs in
// (mat-major, col-panel-major) order -> per-XCD L2 working set
// = Eb (2MB) + 6 B col-panels (0.75MB) < 4MB.
// ---------------------------------------------------------------------------
__global__ __launch_bounds__(256)
void gemm3_mfma(const unsigned short* __restrict__ Eb,
                const unsigned short* __restrict__ Wt,
                const float* __restrict__ bl, const float* __restrict__ ba,
                const float* __restrict__ bh, float* __restrict__ Y) {
  // bijective XCD swizzle (768 % 8 == 0): orig -> chunk-per-XCD job id
  const int orig = blockIdx.x;
  const int job = (orig & 7) * 96 + (orig >> 3);
  const int mat = job >> 8;          // /256
  const int rem = job & 255;
  const int bx = rem >> 4;           // col panel 0..15
  const int by = rem & 15;           // row panel 0..15

  const unsigned short* Bg = Wt + (size_t)mat * DD * DD;
  const float* bias = (mat == 0) ? bl : (mat == 1) ? ba : bh;
  float* Yout = Y + (size_t)mat * DD * DD;

  __shared__ unsigned short As[2][64 * 64];
  __shared__ unsigned short Bs[2][64 * 64];

  const int t = threadIdx.x;
  const int lane = t & 63;
  const int w = t >> 6;            // wave 0..3
  const int wr = w >> 1, wc = w & 1;
  const int brow = by * 64, bcol = bx * 64;

  // staging: thread t -> tile row (t>>3) [+32 for 2nd issue], 16B chunk (t&7).
  // swizzle: LDS row r, linear chunk q holds global chunk q ^ (r&7).
  const int srow = t >> 3;                      // 0..31
  const int sk = (((t & 7) ^ (srow & 7)) * 8);  // source k-offset (elems)
  const unsigned short* gA = Eb + (size_t)(brow + srow) * DD + sk;
  const unsigned short* gB = Bg + (size_t)(bcol + srow) * DD + sk;
  const int ldsoff = w * 512;   // elems; wave-uniform base (+ lane*16B by HW)

  const int lrow = lane & 15, lg = lane >> 4;

  // swizzled fragment indices: row r, logical chunk (kk*4+lg) -> chunk^(r&7)
  int aidx[2][2], bidx[2][2];
  #pragma unroll
  for (int kk = 0; kk < 2; ++kk)
    #pragma unroll
    for (int m = 0; m < 2; ++m) {
      const int ra = wr * 32 + m * 16 + lrow;
      aidx[kk][m] = ra * 64 + (((kk * 4 + lg) ^ (ra & 7)) * 8);
      const int rb = wc * 32 + m * 16 + lrow;
      bidx[kk][m] = rb * 64 + (((kk * 4 + lg) ^ (rb & 7)) * 8);
    }

  f32x4 acc[2][2] = {};

  // prologue: stage tile 0 into buf 0
  GLDS(gA,           &As[0][ldsoff]);
  GLDS(gA + 32 * DD, &As[0][2048 + ldsoff]);
  GLDS(gB,           &Bs[0][ldsoff]);
  GLDS(gB + 32 * DD, &Bs[0][2048 + ldsoff]);
  __syncthreads();   // drains vmcnt -> tile 0 ready

  int cur = 0;
  for (int kt = 0; kt < 16; ++kt) {
    if (kt < 15) {   // prefetch next tile into the other buffer
      const int k0 = (kt + 1) * 64;
      GLDS(gA + k0,           &As[cur ^ 1][ldsoff]);
      GLDS(gA + k0 + 32 * DD, &As[cur ^ 1][2048 + ldsoff]);
      GLDS(gB + k0,           &Bs[cur ^ 1][ldsoff]);
      GLDS(gB + k0 + 32 * DD, &Bs[cur ^ 1][2048 + ldsoff]);
    }

    short8v a[2][2], b[2][2];
    #pragma unroll
    for (int kk = 0; kk < 2; ++kk)
      #pragma unroll
      for (int m = 0; m < 2; ++m) {
        a[kk][m] = *(const short8v*)&As[cur][aidx[kk][m]];
        b[kk][m] = *(const short8v*)&Bs[cur][bidx[kk][m]];
      }

    #pragma unroll
    for (int kk = 0; kk < 2; ++kk)
      #pragma unroll
      for (int m = 0; m < 2; ++m)
        #pragma unroll
        for (int n = 0; n < 2; ++n)
          acc[m][n] = __builtin_amdgcn_mfma_f32_16x16x32_bf16(
              a[kk][m], b[kk][n], acc[m][n], 0, 0, 0);

    __syncthreads();   // drains prefetch (vmcnt 0) + all ds_reads, then barrier
    cur ^= 1;
  }

  // epilogue: bias + relu (C/D: col = lane&15, row = (lane>>4)*4 + j)
  #pragma unroll
  for (int m = 0; m < 2; ++m) {
    #pragma unroll
    for (int n = 0; n < 2; ++n) {
      const int col = bcol + wc * 32 + n * 16 + lrow;
      const int r0  = brow + wr * 32 + m * 16 + lg * 4;
      const float bv = bias[col];
      #pragma unroll
      for (int j = 0; j < 4; ++j)
        Yout[(size_t)(r0 + j) * DD + col] = fmaxf(acc[m][n][j] + bv, 0.f);
    }
  }
}

// ---------------------------------------------------------------------------
// Epilogue: per (b,i) node -- gather neighbor rows of Ya/Yh (float4,
// coalesced), per-head softmax over L=128, head-mean output.
// XCD-swizzled so all 128 nodes of batch b land on one XCD (per-XCD
// working set = batch slabs of Ya/Yh/Yl = 1.5MB, L2-resident).
// ---------------------------------------------------------------------------
__global__ __launch_bounds__(256)
void colight_epilogue(const float* __restrict__ adj,
                      const float* __restrict__ Y,
                      float* __restrict__ out) {
  const int bid = blockIdx.x;
  const int bi = (bid & 7) * NN + (bid >> 3);   // batch = bid&7 -> XCD bid&7
  const int b  = bi >> 7;

  __shared__ int   idxs[KNBR];
  __shared__ float sA[DD];
  __shared__ float sH[DD];
  __shared__ float sL[DD];
  __shared__ float sPart[NH][LL];

  const int t = threadIdx.x;

  // one-hot scan: group k = t>>5 scans its 128-float row as float4
  const float* arow = adj + (size_t)bi * KNBR * NN;
  {
    const int k = t >> 5, j = t & 31;
    float4 v = *(const float4*)&arow[k * NN + j * 4];
    const int base = j * 4;
    if (v.x > 0.5f) idxs[k] = base;
    if (v.y > 0.5f) idxs[k] = base + 1;
    if (v.z > 0.5f) idxs[k] = base + 2;
    if (v.w > 0.5f) idxs[k] = base + 3;
  }
  __syncthreads();

  const float* Yl = Y;
  const float* Ya = Y + (size_t)DD * DD;
  const float* Yh = Y + 2 * (size_t)DD * DD;
  const int rbase = b * NN;

  int ridx[KNBR];
  #pragma unroll
  for (int k = 0; k < KNBR; ++k) ridx[k] = rbase + idxs[k];

  // gather + sum 8 neighbor rows (float4 per thread, coalesced row reads)
  const int d0 = t * 4;
  {
    float ax = 0.f, ay = 0.f, az = 0.f, aw = 0.f;
    float hx = 0.f, hy = 0.f, hz = 0.f, hw = 0.f;
    #pragma unroll
    for (int k = 0; k < KNBR; ++k) {
      const size_t rr = (size_t)ridx[k] * DD + d0;
      float4 va = *(const float4*)&Ya[rr];
      float4 vh = *(const float4*)&Yh[rr];
      ax += va.x; ay += va.y; az += va.z; aw += va.w;
      hx += vh.x; hy += vh.y; hz += vh.z; hw += vh.w;
    }
    float4 sa = {ax, ay, az, aw};
    float4 sh = {hx, hy, hz, hw};
    *(float4*)&sA[d0] = sa;
    *(float4*)&sH[d0] = sh;
    *(float4*)&sL[d0] = *(const float4*)&Yl[(size_t)bi * DD + d0];
  }
  __syncthreads();

  // per-head softmax over L=128: head h = t>>5, lane j = t&31, 4 elems/lane
  const int h = t >> 5, j = t & 31;
  float z[4];
  float mx = -1e30f;
  #pragma unroll
  for (int q = 0; q < 4; ++q) {
    const int l = j + q * 32;
    z[q] = sL[l * NH + h] * sA[l * NH + h];
    mx = fmaxf(mx, z[q]);
  }
  #pragma unroll
  for (int m = 1; m <= 16; m <<= 1)
    mx = fmaxf(mx, __shfl_xor(mx, m, 32));

  float se = 0.f;
  #pragma unroll
  for (int q = 0; q < 4; ++q) {
    z[q] = expf(z[q] - mx);
    se += z[q];
  }
  #pragma unroll
  for (int m = 1; m <= 16; m <<= 1)
    se += __shfl_xor(se, m, 32);
  const float inv = 1.f / se;

  #pragma unroll
  for (int q = 0; q < 4; ++q) {
    const int l = j + q * 32;
    sPart[h][l] = z[q] * inv * sH[l * NH + h] * 0.125f;  // mean over 8 heads
  }
  __syncthreads();

  if (t < LL) {
    float o = 0.f;
    #pragma unroll
    for (int hh = 0; hh < NH; ++hh) o += sPart[hh][t];
    out[(size_t)bi * LL + t] = o;
  }
}

// ---------------------------------------------------------------------------
extern "C" void kernel_launch(void* const* d_in, const int* in_sizes, int n_in,
                              void* d_out, int out_size, void* d_ws, size_t ws_size,
                              hipStream_t stream) {
  const float* E   = (const float*)d_in[0];
  const float* adj = (const float*)d_in[1];
  const float* Wl  = (const float*)d_in[2];
  const float* bl  = (const float*)d_in[3];
  const float* Wa  = (const float*)d_in[4];
  const float* ba  = (const float*)d_in[5];
  const float* Wh  = (const float*)d_in[6];
  const float* bh  = (const float*)d_in[7];
  float* out = (float*)d_out;

  char* ws = (char*)d_ws;
  float*          Y  = (float*)ws;                               // 12 MB
  unsigned short* Eb = (unsigned short*)(ws + 12 * 1024 * 1024); // 2 MB
  unsigned short* Wt = (unsigned short*)(ws + 14 * 1024 * 1024); // 6 MB

  prep<<<dim3(16, 16, 4), dim3(256), 0, stream>>>(E, Wl, Wa, Wh, Eb, Wt);
  gemm3_mfma<<<dim3(768), dim3(256), 0, stream>>>(Eb, Wt, bl, ba, bh, Y);
  colight_epilogue<<<dim3(BB * NN), dim3(256), 0, stream>>>(adj, Y, out);
}

// Round 5
// 28.892 us; speedup vs baseline: 3.8101x; 1.1535x over previous
//
#include <hip/hip_runtime.h>
#include <math.h>

#define DD 1024   // total dim
#define NN 128    // nodes
#define BB 8      // batch
#define KNBR 8    // neighbors
#define NH 8      // heads
#define LL 128    // latent

typedef __attribute__((ext_vector_type(8))) short short8v;
typedef __attribute__((ext_vector_type(4))) float f32x4;

#define GLDS(gptr, lptr)                                                      \
  __builtin_amdgcn_global_load_lds(                                           \
      (const __attribute__((address_space(1))) void*)(gptr),                  \
      (__attribute__((address_space(3))) void*)(lptr), 16, 0, 0)

__device__ __forceinline__ unsigned short f2bf(float x) {
  unsigned u = __float_as_uint(x);
  unsigned r = u + 0x7fff + ((u >> 16) & 1);   // round-to-nearest-even
  return (unsigned short)(r >> 16);
}
__device__ __forceinline__ float bf2f(unsigned short u) {
  return __uint_as_float((unsigned)u << 16);
}

// ---------------------------------------------------------------------------
// Prep: z<3 -> convert+transpose W[z] (64x64 LDS tiles); z==3 -> convert E.
// grid (16,16,4), 256 threads.
// ---------------------------------------------------------------------------
__global__ __launch_bounds__(256)
void prep(const float* __restrict__ E,
          const float* __restrict__ Wl, const float* __restrict__ Wa,
          const float* __restrict__ Wh,
          unsigned short* __restrict__ Eb, unsigned short* __restrict__ Wt) {
  const int z = blockIdx.z;
  const int t = threadIdx.x;

  if (z == 3) {   // E convert: 256 blocks x 256 threads x 16 elems
    const int bid = blockIdx.y * 16 + blockIdx.x;
    const int i0 = bid * 4096 + t * 16;
    #pragma unroll
    for (int q = 0; q < 2; ++q) {
      const int i = i0 + q * 8;
      float4 a = *(const float4*)&E[i];
      float4 c = *(const float4*)&E[i + 4];
      union { unsigned short u[8]; uint4 v; } o;
      o.u[0] = f2bf(a.x); o.u[1] = f2bf(a.y); o.u[2] = f2bf(a.z); o.u[3] = f2bf(a.w);
      o.u[4] = f2bf(c.x); o.u[5] = f2bf(c.y); o.u[6] = f2bf(c.z); o.u[7] = f2bf(c.w);
      *(uint4*)&Eb[i] = o.v;
    }
    return;
  }

  const float* W = (z == 0) ? Wl : (z == 1) ? Wa : Wh;
  unsigned short* out = Wt + (size_t)z * DD * DD;

  __shared__ unsigned short tile[64][65];
  const int tx = t & 15, ty = t >> 4;
  const int r0 = blockIdx.y * 64, c0 = blockIdx.x * 64;

  #pragma unroll
  for (int i = 0; i < 4; ++i) {
    const int r = ty + i * 16;
    float4 v = *(const float4*)&W[(size_t)(r0 + r) * DD + c0 + tx * 4];
    tile[r][tx * 4 + 0] = f2bf(v.x);
    tile[r][tx * 4 + 1] = f2bf(v.y);
    tile[r][tx * 4 + 2] = f2bf(v.z);
    tile[r][tx * 4 + 3] = f2bf(v.w);
  }
  __syncthreads();
  #pragma unroll
  for (int i = 0; i < 4; ++i) {
    const int rr = ty + i * 16;   // output row = W column c0+rr
    ushort4 o;
    o.x = tile[tx * 4 + 0][rr];
    o.y = tile[tx * 4 + 1][rr];
    o.z = tile[tx * 4 + 2][rr];
    o.w = tile[tx * 4 + 3][rr];
    *(ushort4*)&out[(size_t)(c0 + rr) * DD + r0 + tx * 4] = o;
  }
}

// ---------------------------------------------------------------------------
// MFMA GEMM: Yl = relu(Eb@Wl+bl) fp32; Ya/Yh = same in bf16.
// 64x64 tile, BK=64, 256 threads = 4 waves, wave tile 32x32.
// 3-buffer LDS, 2-tile-deep prefetch with counted vmcnt(4) + raw s_barrier
// (one barrier per K-step, prefetch never drained mid-loop).
// XOR-swizzled tiles (pre-swizzled global source + swizzled ds_read index).
// 1D grid 768, bijective XCD swizzle (per-XCD L2 set: Eb + 6 B-panels < 4MB).
// ---------------------------------------------------------------------------
__global__ __launch_bounds__(256)
void gemm3_mfma(const unsigned short* __restrict__ Eb,
                const unsigned short* __restrict__ Wt,
                const float* __restrict__ bl, const float* __restrict__ ba,
                const float* __restrict__ bh,
                float* __restrict__ Yl, unsigned short* __restrict__ Yab,
                unsigned short* __restrict__ Yhb) {
  const int orig = blockIdx.x;
  const int job = (orig & 7) * 96 + (orig >> 3);
  const int mat = job >> 8;          // /256
  const int rem = job & 255;
  const int bx = rem >> 4;           // col panel 0..15
  const int by = rem & 15;           // row panel 0..15

  const unsigned short* Bg = Wt + (size_t)mat * DD * DD;
  const float* bias = (mat == 0) ? bl : (mat == 1) ? ba : bh;

  __shared__ unsigned short As[3][64 * 64];
  __shared__ unsigned short Bs[3][64 * 64];

  const int t = threadIdx.x;
  const int lane = t & 63;
  const int w = t >> 6;            // wave 0..3
  const int wr = w >> 1, wc = w & 1;
  const int brow = by * 64, bcol = bx * 64;

  // staging: thread t -> tile row (t>>3) [+32 for 2nd issue], 16B chunk (t&7).
  // swizzle: LDS row r, linear chunk q holds global chunk q ^ (r&7).
  const int srow = t >> 3;                      // 0..31
  const int sk = (((t & 7) ^ (srow & 7)) * 8);  // source k-offset (elems)
  const unsigned short* gA = Eb + (size_t)(brow + srow) * DD + sk;
  const unsigned short* gB = Bg + (size_t)(bcol + srow) * DD + sk;
  const int ldsoff = w * 512;   // elems; wave-uniform base (+ lane*16B by HW)

  const int lrow = lane & 15, lg = lane >> 4;

  // swizzled fragment indices: row r, logical chunk (kk*4+lg) -> chunk^(r&7)
  int aidx[2][2], bidx[2][2];
  #pragma unroll
  for (int kk = 0; kk < 2; ++kk)
    #pragma unroll
    for (int m = 0; m < 2; ++m) {
      const int ra = wr * 32 + m * 16 + lrow;
      aidx[kk][m] = ra * 64 + (((kk * 4 + lg) ^ (ra & 7)) * 8);
      const int rb = wc * 32 + m * 16 + lrow;
      bidx[kk][m] = rb * 64 + (((kk * 4 + lg) ^ (rb & 7)) * 8);
    }

  // preload bias and force completion so loop vmcnt counting stays exact
  float bv0 = bias[bcol + wc * 32 + lrow];
  float bv1 = bias[bcol + wc * 32 + 16 + lrow];
  asm volatile("" : "+v"(bv0), "+v"(bv1));   // materialize (drains their loads)

  f32x4 acc[2][2] = {};

#define STAGE(q, kt) do {                                                     \
    const int k0_ = (kt) * 64;                                                \
    GLDS(gA + k0_,           &As[q][ldsoff]);                                 \
    GLDS(gA + k0_ + 32 * DD, &As[q][2048 + ldsoff]);                          \
    GLDS(gB + k0_,           &Bs[q][ldsoff]);                                 \
    GLDS(gB + k0_ + 32 * DD, &Bs[q][2048 + ldsoff]);                          \
  } while (0)

  STAGE(0, 0);   // 4 vm ops in flight
  STAGE(1, 1);   // 8 in flight

  #pragma unroll
  for (int kt = 0; kt < 16; ++kt) {
    const int p = kt % 3;
    // wait for tile kt's 4 loads (oldest); tile kt+1's 4 stay in flight
    if (kt != 15) asm volatile("s_waitcnt vmcnt(4)" ::: "memory");
    else          asm volatile("s_waitcnt vmcnt(0)" ::: "memory");
    __builtin_amdgcn_s_barrier();   // all waves' slices of buf p landed;
                                    // also: all reads of buf (p+2)%3 done
    if (kt + 2 < 16) STAGE((kt + 2) % 3, kt + 2);   // overwrite tile kt-1's buf

    short8v a[2][2], b[2][2];
    #pragma unroll
    for (int kk = 0; kk < 2; ++kk)
      #pragma unroll
      for (int m = 0; m < 2; ++m) {
        a[kk][m] = *(const short8v*)&As[p][aidx[kk][m]];
        b[kk][m] = *(const short8v*)&Bs[p][bidx[kk][m]];
      }

    #pragma unroll
    for (int kk = 0; kk < 2; ++kk)
      #pragma unroll
      for (int m = 0; m < 2; ++m)
        #pragma unroll
        for (int n = 0; n < 2; ++n)
          acc[m][n] = __builtin_amdgcn_mfma_f32_16x16x32_bf16(
              a[kk][m], b[kk][n], acc[m][n], 0, 0, 0);
  }
#undef STAGE

  // epilogue: bias + relu (C/D: col = lane&15, row = (lane>>4)*4 + j)
  #pragma unroll
  for (int m = 0; m < 2; ++m) {
    #pragma unroll
    for (int n = 0; n < 2; ++n) {
      const int col = bcol + wc * 32 + n * 16 + lrow;
      const int r0  = brow + wr * 32 + m * 16 + lg * 4;
      const float bv = n ? bv1 : bv0;
      if (mat == 0) {
        #pragma unroll
        for (int j = 0; j < 4; ++j)
          Yl[(size_t)(r0 + j) * DD + col] = fmaxf(acc[m][n][j] + bv, 0.f);
      } else {
        unsigned short* Yo = (mat == 1) ? Yab : Yhb;
        #pragma unroll
        for (int j = 0; j < 4; ++j)
          Yo[(size_t)(r0 + j) * DD + col] = f2bf(fmaxf(acc[m][n][j] + bv, 0.f));
      }
    }
  }
}

// ---------------------------------------------------------------------------
// Epilogue: per (b,i) node -- gather neighbor rows of Ya/Yh (bf16, short4
// coalesced), per-head softmax over L=128 (fp32 Yl), head-mean output.
// XCD-swizzled: batch b -> XCD b (per-XCD set = batch slabs, L2-resident).
// ---------------------------------------------------------------------------
__global__ __launch_bounds__(256)
void colight_epilogue(const float* __restrict__ adj,
                      const float* __restrict__ Yl,
                      const unsigned short* __restrict__ Yab,
                      const unsigned short* __restrict__ Yhb,
                      float* __restrict__ out) {
  const int bid = blockIdx.x;
  const int bi = (bid & 7) * NN + (bid >> 3);   // batch = bid&7 -> XCD bid&7
  const int b  = bi >> 7;

  __shared__ int   idxs[KNBR];
  __shared__ float sA[DD];
  __shared__ float sH[DD];
  __shared__ float sL[DD];
  __shared__ float sPart[NH][LL];

  const int t = threadIdx.x;

  // one-hot scan: group k = t>>5 scans its 128-float row as float4
  const float* arow = adj + (size_t)bi * KNBR * NN;
  {
    const int k = t >> 5, j = t & 31;
    float4 v = *(const float4*)&arow[k * NN + j * 4];
    const int base = j * 4;
    if (v.x > 0.5f) idxs[k] = base;
    if (v.y > 0.5f) idxs[k] = base + 1;
    if (v.z > 0.5f) idxs[k] = base + 2;
    if (v.w > 0.5f) idxs[k] = base + 3;
  }
  __syncthreads();

  const int rbase = b * NN;
  int ridx[KNBR];
  #pragma unroll
  for (int k = 0; k < KNBR; ++k) ridx[k] = rbase + idxs[k];

  // gather + sum 8 neighbor rows (short4 = 8B/lane, coalesced row segments)
  const int d0 = t * 4;
  {
    float a0 = 0.f, a1 = 0.f, a2 = 0.f, a3 = 0.f;
    float h0 = 0.f, h1 = 0.f, h2 = 0.f, h3 = 0.f;
    #pragma unroll
    for (int k = 0; k < KNBR; ++k) {
      const size_t rr = (size_t)ridx[k] * DD + d0;
      ushort4 va = *(const ushort4*)&Yab[rr];
      ushort4 vh = *(const ushort4*)&Yhb[rr];
      a0 += bf2f(va.x); a1 += bf2f(va.y); a2 += bf2f(va.z); a3 += bf2f(va.w);
      h0 += bf2f(vh.x); h1 += bf2f(vh.y); h2 += bf2f(vh.z); h3 += bf2f(vh.w);
    }
    float4 sa = {a0, a1, a2, a3};
    float4 sh = {h0, h1, h2, h3};
    *(float4*)&sA[d0] = sa;
    *(float4*)&sH[d0] = sh;
    *(float4*)&sL[d0] = *(const float4*)&Yl[(size_t)bi * DD + d0];
  }
  __syncthreads();

  // per-head softmax over L=128: head h = t>>5, lane j = t&31, 4 elems/lane
  const int h = t >> 5, j = t & 31;
  float z[4];
  float mx = -1e30f;
  #pragma unroll
  for (int q = 0; q < 4; ++q) {
    const int l = j + q * 32;
    z[q] = sL[l * NH + h] * sA[l * NH + h];
    mx = fmaxf(mx, z[q]);
  }
  #pragma unroll
  for (int m = 1; m <= 16; m <<= 1)
    mx = fmaxf(mx, __shfl_xor(mx, m, 32));

  float se = 0.f;
  #pragma unroll
  for (int q = 0; q < 4; ++q) {
    z[q] = expf(z[q] - mx);
    se += z[q];
  }
  #pragma unroll
  for (int m = 1; m <= 16; m <<= 1)
    se += __shfl_xor(se, m, 32);
  const float inv = 1.f / se;

  #pragma unroll
  for (int q = 0; q < 4; ++q) {
    const int l = j + q * 32;
    sPart[h][l] = z[q] * inv * sH[l * NH + h] * 0.125f;  // mean over 8 heads
  }
  __syncthreads();

  if (t < LL) {
    float o = 0.f;
    #pragma unroll
    for (int hh = 0; hh < NH; ++hh) o += sPart[hh][t];
    out[(size_t)bi * LL + t] = o;
  }
}

// ---------------------------------------------------------------------------
extern "C" void kernel_launch(void* const* d_in, const int* in_sizes, int n_in,
                              void* d_out, int out_size, void* d_ws, size_t ws_size,
                              hipStream_t stream) {
  const float* E   = (const float*)d_in[0];
  const float* adj = (const float*)d_in[1];
  const float* Wl  = (const float*)d_in[2];
  const float* bl  = (const float*)d_in[3];
  const float* Wa  = (const float*)d_in[4];
  const float* ba  = (const float*)d_in[5];
  const float* Wh  = (const float*)d_in[6];
  const float* bh  = (const float*)d_in[7];
  float* out = (float*)d_out;

  char* ws = (char*)d_ws;
  float*          Yl  = (float*)ws;                                // 4 MB
  unsigned short* Yab = (unsigned short*)(ws + 4  * 1024 * 1024);  // 2 MB
  unsigned short* Yhb = (unsigned short*)(ws + 6  * 1024 * 1024);  // 2 MB
  unsigned short* Eb  = (unsigned short*)(ws + 8  * 1024 * 1024);  // 2 MB
  unsigned short* Wt  = (unsigned short*)(ws + 10 * 1024 * 1024);  // 6 MB

  prep<<<dim3(16, 16, 4), dim3(256), 0, stream>>>(E, Wl, Wa, Wh, Eb, Wt);
  gemm3_mfma<<<dim3(768), dim3(256), 0, stream>>>(Eb, Wt, bl, ba, bh,
                                                  Yl, Yab, Yhb);
  colight_epilogue<<<dim3(BB * NN), dim3(256), 0, stream>>>(adj, Yl, Yab, Yhb, out);
}